// Round 13
// baseline (588.053 us; speedup 1.0000x reference)
//
#include <hip/hip_runtime.h>

// ---------------------------------------------------------------------------
// GAT fraud detector, round 8:
//  - DISCRIMINATING EXPERIMENT on agg kernels. Evidence: FETCH pinned at
//    215.7MB (= 8-XCD compulsory floor for random gather of 25.6MB hb) across
//    3 structurally different kernels, all 66-68us (~3.2 TB/s effective);
//    r7b cut VALUBusy 64->53% with zero dur change. Either the L3->L2 fill
//    path saturates at ~3.2 TB/s (agg4 at floor) or the shared
//    one-node-per-block structure is the confound.
//  - agg v2: 4 nodes per block, ONE 32-lane group per node owning all 256 ch
//    (8/lane). Kills lsum cross-group combine + per-node barriers (2 barriers
//    amortized over 4 nodes), 16 serial edges/group with depth-8 rolling
//    pipeline (8 rows in flight/group, was 4), single uint4 store per lane.
//    CAP 64 (deg~Binom mean 16 sd 4; max over 50k nodes ~40) + slow path.
//  - rest identical to round 7b (MFMA GEMM + fused sd + XCD-pair swizzle,
//    parallel scan, vectorized BN/pool partials).
// ---------------------------------------------------------------------------

typedef unsigned int uint;
typedef unsigned short ushort;

#define NEG_SLOPE 0.2f
#define BN_EPS 1e-5f
#define NB_RED 256   // blocks for BN-stats / pool partial reductions

typedef __attribute__((ext_vector_type(2))) float f32x2;

__device__ __forceinline__ float bf2f(uint u) { return __uint_as_float(u << 16); }
__device__ __forceinline__ ushort f2bf(float f) {
    uint u = __float_as_uint(f);
    u += 0x7fff + ((u >> 16) & 1);   // round-nearest-even
    return (ushort)(u >> 16);
}

// ---------------- fused prep: cvt x -> bf16 (padded), transpose weights, histogram ----------------

__global__ void prep_kernel(const float* __restrict__ x, ushort* __restrict__ xb,
                            int total_real, int total_pad,
                            const float* __restrict__ W0, ushort* __restrict__ w0t,
                            const float* __restrict__ W1, ushort* __restrict__ w1t,
                            const float* __restrict__ W2, ushort* __restrict__ w2t,
                            const int* __restrict__ ei, int* __restrict__ deg, int E) {
    int i = blockIdx.x * blockDim.x + threadIdx.x;
    if (i < total_pad) {
        xb[i] = (i < total_real) ? f2bf(x[i]) : (ushort)0;
        return;
    }
    int j = i - total_pad;
    if (j < 32768) {                        // W0: K=128,F=256
        int n = j / 128, k = j - n * 128;
        w0t[j] = f2bf(W0[(size_t)k * 256 + n]);
        return;
    }
    j -= 32768;
    if (j < 65536) {                        // W1: K=256,F=256
        int n = j / 256, k = j - n * 256;
        w1t[j] = f2bf(W1[(size_t)k * 256 + n]);
        return;
    }
    j -= 65536;
    if (j < 16384) {                        // W2: K=256,F=64
        int n = j / 256, k = j - n * 256;
        w2t[j] = f2bf(W2[(size_t)k * 64 + n]);
        return;
    }
    j -= 16384;
    if (j < E) atomicAdd(&deg[ei[E + j]], 1);
}

// ---------------- CSR scan + scatter ----------------

__global__ void scan_part(const int* __restrict__ deg, int* __restrict__ offsets,
                          int* __restrict__ bsum, int N) {
    __shared__ int sh[256];
    int t = threadIdx.x;
    int base = blockIdx.x * 1024 + t * 4;
    int v0 = (base + 0 < N) ? deg[base + 0] : 0;
    int v1 = (base + 1 < N) ? deg[base + 1] : 0;
    int v2 = (base + 2 < N) ? deg[base + 2] : 0;
    int v3 = (base + 3 < N) ? deg[base + 3] : 0;
    int s = v0 + v1 + v2 + v3;
    sh[t] = s;
    __syncthreads();
    for (int off = 1; off < 256; off <<= 1) {
        int y = (t >= off) ? sh[t - off] : 0;
        __syncthreads();
        sh[t] += y;
        __syncthreads();
    }
    int p = sh[t] - s;
    if (base + 0 < N) offsets[base + 0] = p;
    p += v0;
    if (base + 1 < N) offsets[base + 1] = p;
    p += v1;
    if (base + 2 < N) offsets[base + 2] = p;
    p += v2;
    if (base + 3 < N) offsets[base + 3] = p;
    if (t == 255) bsum[blockIdx.x] = sh[255];
}

__global__ void scan_top(const int* __restrict__ bsum, int* __restrict__ bexcl,
                         int nb, int* __restrict__ offsets, int N) {
    if (threadIdx.x == 0) {
        int run = 0;
        for (int b = 0; b < nb; ++b) { bexcl[b] = run; run += bsum[b]; }
        offsets[N] = run;
    }
}

__global__ void scan_add(int* __restrict__ offsets, int* __restrict__ cursor,
                         const int* __restrict__ bexcl, int N) {
    int add = bexcl[blockIdx.x];
    int base = blockIdx.x * 1024 + threadIdx.x * 4;
#pragma unroll
    for (int k = 0; k < 4; ++k) {
        int i = base + k;
        if (i < N) { int v = offsets[i] + add; offsets[i] = v; cursor[i] = v; }
    }
}

__global__ void scatter_kernel(const int* __restrict__ ei, int* __restrict__ cursor,
                               int* __restrict__ srcs, int E) {
    int e = blockIdx.x * blockDim.x + threadIdx.x;
    if (e < E) {
        int s = ei[e];
        int d = ei[E + e];
        int p = atomicAdd(&cursor[d], 1);
        srcs[p] = s;
    }
}

// ---------------- bf16 MFMA GEMM with fused sd epilogue ----------------

typedef __attribute__((ext_vector_type(8))) short bf16x8;
typedef __attribute__((ext_vector_type(4))) float floatx4;

template <int BN, int H>
__launch_bounds__(256)
__global__ void mfma_gemm_bt(const ushort* __restrict__ A, const ushort* __restrict__ Bt,
                             ushort* __restrict__ C, const float* __restrict__ asrc,
                             const float* __restrict__ adst, float* __restrict__ sv,
                             float* __restrict__ dv, int K, int Nn) {
    constexpr int WCOLS = (BN == 128) ? 2 : 1;
    constexpr int WROWS = 4 / WCOLS;
    constexpr int MT = 128 / (WROWS * 16);
    constexpr int NT = BN / (WCOLS * 16);
    constexpr int BCALLS = (BN * 32 * 2) / 4096;

    __shared__ ushort As[128 * 32];
    __shared__ ushort Bs[BN * 32];

    int t = threadIdx.x;
    int w = t >> 6, l = t & 63;

    // block -> tile mapping. For the 2-column-block layers (BN==128), use a
    // 1D grid with an XCD-pairing swizzle: ids d and d+8 are (same row tile,
    // col 0/1) and share d%8 -> same XCD L2 -> second A-panel read is L2-hit.
    int rb, cb;
    if (BN == 128) {
        int nbr = (int)gridDim.x >> 1;       // row tiles
        int full = (nbr & ~7) << 1;
        int id = blockIdx.x;
        if (id < full) {
            rb = ((id >> 4) << 3) + (id & 7);
            cb = (id >> 3) & 1;
        } else {
            int o = id - full;
            int rem = nbr & 7;
            rb = (nbr & ~7) + (rem ? (o % rem) : 0);
            cb = rem ? (o / rem) : 0;
        }
    } else {
        rb = blockIdx.x;
        cb = 0;
    }
    int row0 = rb * 128;
    int col0 = cb * BN;
    int wr = (w / WCOLS) * (MT * 16);
    int wc = (w % WCOLS) * (NT * 16);

    floatx4 acc[MT][NT];
#pragma unroll
    for (int mi = 0; mi < MT; ++mi)
#pragma unroll
        for (int ni = 0; ni < NT; ++ni)
#pragma unroll
            for (int r = 0; r < 4; ++r) acc[mi][ni][r] = 0.f;

    int mrow = l & 15;
    int kc = (l >> 4) * 8;

    for (int kt = 0; kt < K; kt += 32) {
#pragma unroll
        for (int c = 0; c < 2; ++c) {
            int idx = c * 256 + t;
            const ushort* gp = A + (size_t)(row0 + (idx >> 2)) * K + kt + (idx & 3) * 8;
            __builtin_amdgcn_global_load_lds(
                (const __attribute__((address_space(1))) void*)gp,
                (__attribute__((address_space(3))) void*)(As + (idx & ~63) * 8),
                16, 0, 0);
        }
#pragma unroll
        for (int c = 0; c < BCALLS; ++c) {
            int idx = c * 256 + t;
            const ushort* gp = Bt + (size_t)(col0 + (idx >> 2)) * K + kt + (idx & 3) * 8;
            __builtin_amdgcn_global_load_lds(
                (const __attribute__((address_space(1))) void*)gp,
                (__attribute__((address_space(3))) void*)(Bs + (idx & ~63) * 8),
                16, 0, 0);
        }
        __syncthreads();

        bf16x8 af[MT], bfr[NT];
#pragma unroll
        for (int mi = 0; mi < MT; ++mi)
            af[mi] = *(const bf16x8*)&As[(wr + mi * 16 + mrow) * 32 + kc];
#pragma unroll
        for (int ni = 0; ni < NT; ++ni)
            bfr[ni] = *(const bf16x8*)&Bs[(wc + ni * 16 + mrow) * 32 + kc];
#pragma unroll
        for (int mi = 0; mi < MT; ++mi)
#pragma unroll
            for (int ni = 0; ni < NT; ++ni)
                acc[mi][ni] = __builtin_amdgcn_mfma_f32_16x16x32_bf16(
                    af[mi], bfr[ni], acc[mi][ni], 0, 0, 0);
        __syncthreads();
    }

    // C store (C/D layout: col=lane&15, row=(lane>>4)*4+reg)
#pragma unroll
    for (int mi = 0; mi < MT; ++mi) {
        int rbase = row0 + wr + mi * 16 + (l >> 4) * 4;
#pragma unroll
        for (int ni = 0; ni < NT; ++ni) {
            int col = col0 + wc + ni * 16 + (l & 15);
#pragma unroll
            for (int r = 0; r < 4; ++r)
                C[(size_t)(rbase + r) * Nn + col] = f2bf(acc[mi][ni][r]);
        }
    }

    // fused sd: this wave's NT*16 cols lie in exactly one head (64 cols).
    float av[NT], bv[NT];
#pragma unroll
    for (int ni = 0; ni < NT; ++ni) {
        int ch = col0 + wc + ni * 16 + (l & 15);
        av[ni] = asrc[ch];
        bv[ni] = adst[ch];
    }
    int gh = (col0 + wc) >> 6;
#pragma unroll
    for (int mi = 0; mi < MT; ++mi) {
#pragma unroll
        for (int r = 0; r < 4; ++r) {
            float s = 0.f, d = 0.f;
#pragma unroll
            for (int ni = 0; ni < NT; ++ni) {
                float hv = acc[mi][ni][r];
                s += hv * av[ni];
                d += hv * bv[ni];
            }
#pragma unroll
            for (int m = 8; m >= 1; m >>= 1) {
                s += __shfl_xor(s, m);
                d += __shfl_xor(d, m);
            }
            if ((l & 15) == 0) {
                int row = row0 + wr + mi * 16 + (l >> 4) * 4 + r;
                sv[row * H + gh] = s;
                dv[row * H + gh] = d;
            }
        }
    }
}

// ---------------- softmax aggregation v2: 4 nodes/block, 1 group per node ----------------
// agg4: 128 threads = 4 nodes x 32 lanes. Lane gl of node-group sub owns
// channels [gl*8, gl*8+8) -> the group covers all 256 ch, no cross-group
// combine, no lsum. Edges processed serially per group with a depth-8
// rolling pipeline (process 4 / prefetch 4). Weights staged once per
// (edge,head) in LDS; per-(node,head) denominator via LDS atomics.
// NOTE: macro params must NOT be named x/y/z/w (uint4 member capture).

#define CAP4 64

#define ACCUMW4(qv_, wt_) { \
    f32x2 wv_ = {(wt_), (wt_)}; \
    uint pr_[4] = {(qv_).x, (qv_).y, (qv_).z, (qv_).w}; \
    _Pragma("unroll") \
    for (int k_ = 0; k_ < 4; ++k_) { \
        f32x2 hv_ = {__uint_as_float(pr_[k_] << 16), \
                     __uint_as_float(pr_[k_] & 0xffff0000u)}; \
        ax[k_] += wv_ * hv_; \
    } }

#define LDQ4(kk_, wv_, qv_) { \
    int kq_ = (kk_); \
    if (kq_ < scnt) { \
        int nq_ = sidx[sub][kq_]; \
        wv_ = swgt[sub][kq_][head]; \
        qv_ = *(const uint4*)(hrow + (size_t)nq_ * 256); \
    } else { wv_ = 0.f; qv_.x = 0; qv_.y = 0; qv_.z = 0; qv_.w = 0; } }

__launch_bounds__(128)
__global__ void agg4_kernel(const ushort* __restrict__ hb, const float* __restrict__ sv,
                            const float* __restrict__ dv, const int* __restrict__ offsets,
                            const int* __restrict__ srcs, const float* __restrict__ bias,
                            ushort* __restrict__ zb, int N) {
    __shared__ int   sidx[4][CAP4];
    __shared__ float swgt[4][CAP4][4];
    __shared__ float lden[4][4];

    int t = threadIdx.x;
    int sub = t >> 5, gl = t & 31;
    int head = gl >> 3;
    int i = blockIdx.x * 4 + sub;
    bool valid = i < N;

    int beg = 0, cnt = 0;
    if (valid) { beg = offsets[i]; cnt = offsets[i + 1] - beg; }
    int scnt = cnt < CAP4 ? cnt : CAP4;

    // ---- P1: indices (per-group, coalesced) ----
    if (gl < 4) lden[sub][gl] = 0.f;
    for (int k = gl; k < scnt; k += 32) sidx[sub][k] = srcs[beg + k];
    __syncthreads();

    // ---- P2: weights, one exp per (edge,head); lane's h = gl&3 is fixed ----
    {
        int h = gl & 3;
        float dvh = valid ? dv[i * 4 + h] : 0.f;
        float denp = 0.f;
        for (int idx = gl; idx < scnt * 4; idx += 32) {
            int k = idx >> 2;
            float e = sv[sidx[sub][k] * 4 + h] + dvh;
            float wgt = __expf(fminf(fmaxf(e, NEG_SLOPE * e), 60.f));
            swgt[sub][k][h] = wgt;
            denp += wgt;
        }
        atomicAdd(&lden[sub][h], denp);
    }
    __syncthreads();

    // ---- P3: depth-8 rolling row-gather accumulate (process 4, prefetch 4) ----
    f32x2 ax[4] = {};                   // channels {gl*8+2k, gl*8+2k+1}
    const ushort* hrow = hb + gl * 8;   // + srcn*256

    float w0, w1, w2, w3;
    uint4 q0, q1, q2, q3;
    LDQ4(0, w0, q0); LDQ4(1, w1, q1); LDQ4(2, w2, q2); LDQ4(3, w3, q3);
    for (int k = 0; k < scnt; k += 4) {
        float v0 = w0, v1 = w1, v2 = w2, v3 = w3;
        uint4 p0 = q0, p1 = q1, p2 = q2, p3 = q3;
        LDQ4(k + 4, w0, q0); LDQ4(k + 5, w1, q1);
        LDQ4(k + 6, w2, q2); LDQ4(k + 7, w3, q3);
        ACCUMW4(p0, v0);
        ACCUMW4(p1, v1);
        ACCUMW4(p2, v2);
        ACCUMW4(p3, v3);
    }

    // ---- slow path: degree beyond CAP4 (never taken for this input) ----
    if (cnt > CAP4) {
        float d_i = dv[i * 4 + head];
        for (int k2 = CAP4; k2 < cnt; ++k2) {
            int n = srcs[beg + k2];
            float e = sv[n * 4 + head] + d_i;
            float wgt = __expf(fminf(fmaxf(e, NEG_SLOPE * e), 60.f));
            if ((gl & 7) == 0) atomicAdd(&lden[sub][head], wgt);
            uint4 q4 = *(const uint4*)(hrow + (size_t)n * 256);
            ACCUMW4(q4, wgt);
        }
    }

    // ---- final: self edge + normalize + bias; lane stores its 8 ch (16B) ----
    if (valid) {
        float e_self = sv[i * 4 + head] + dv[i * 4 + head];
        float wself = __expf(fminf(fmaxf(e_self, NEG_SLOPE * e_self), 60.f));
        uint4 qs = *(const uint4*)&hb[(size_t)i * 256 + gl * 8];
        ACCUMW4(qs, wself);
        float rden = 1.f / (lden[sub][head] + wself + 1e-16f);
        const float* bb = bias + gl * 8;
        uint4 o;
        o.x = (uint)f2bf(ax[0].x * rden + bb[0]) | ((uint)f2bf(ax[0].y * rden + bb[1]) << 16);
        o.y = (uint)f2bf(ax[1].x * rden + bb[2]) | ((uint)f2bf(ax[1].y * rden + bb[3]) << 16);
        o.z = (uint)f2bf(ax[2].x * rden + bb[4]) | ((uint)f2bf(ax[2].y * rden + bb[5]) << 16);
        o.w = (uint)f2bf(ax[3].x * rden + bb[6]) | ((uint)f2bf(ax[3].y * rden + bb[7]) << 16);
        *(uint4*)&zb[(size_t)i * 256 + gl * 8] = o;
    }
}

// agg1 (H=1, 64 ch): 64 threads = 4 nodes x 16 lanes; lane owns 4 ch (uint2).

#define CAP1 64

#define ACCUMW1(qv_, wt_) { \
    f32x2 wv_ = {(wt_), (wt_)}; \
    f32x2 h0_ = {__uint_as_float((qv_).x << 16), __uint_as_float((qv_).x & 0xffff0000u)}; \
    f32x2 h1_ = {__uint_as_float((qv_).y << 16), __uint_as_float((qv_).y & 0xffff0000u)}; \
    ax[0] += wv_ * h0_; \
    ax[1] += wv_ * h1_; }

#define LDQ1(kk_, wv_, qv_) { \
    int kq_ = (kk_); \
    if (kq_ < scnt) { \
        int nq_ = sidx[sub][kq_]; \
        wv_ = swgt[sub][kq_]; \
        qv_ = *(const uint2*)(hrow + (size_t)nq_ * 64); \
    } else { wv_ = 0.f; qv_.x = 0; qv_.y = 0; } }

__launch_bounds__(64)
__global__ void agg1_kernel(const ushort* __restrict__ hb, const float* __restrict__ sv,
                            const float* __restrict__ dv, const int* __restrict__ offsets,
                            const int* __restrict__ srcs, const float* __restrict__ bias,
                            ushort* __restrict__ zb, int N) {
    __shared__ int   sidx[4][CAP1];
    __shared__ float swgt[4][CAP1];
    __shared__ float lden[4];

    int t = threadIdx.x;
    int sub = t >> 4, gl = t & 15;
    int i = blockIdx.x * 4 + sub;
    bool valid = i < N;

    int beg = 0, cnt = 0;
    if (valid) { beg = offsets[i]; cnt = offsets[i + 1] - beg; }
    int scnt = cnt < CAP1 ? cnt : CAP1;

    // ---- P1: indices ----
    if (gl == 0) lden[sub] = 0.f;
    for (int k = gl; k < scnt; k += 16) sidx[sub][k] = srcs[beg + k];
    __syncthreads();

    // ---- P2: weights (one exp per edge) ----
    float d_i = valid ? dv[i] : 0.f;
    {
        float denp = 0.f;
        for (int k = gl; k < scnt; k += 16) {
            float e = sv[sidx[sub][k]] + d_i;
            float wgt = __expf(fminf(fmaxf(e, NEG_SLOPE * e), 60.f));
            swgt[sub][k] = wgt;
            denp += wgt;
        }
        atomicAdd(&lden[sub], denp);
    }
    __syncthreads();

    // ---- P3: depth-8 rolling gather accumulate ----
    f32x2 ax[2] = {};
    const ushort* hrow = hb + gl * 4;   // + srcn*64

    float w0, w1, w2, w3;
    uint2 q0, q1, q2, q3;
    LDQ1(0, w0, q0); LDQ1(1, w1, q1); LDQ1(2, w2, q2); LDQ1(3, w3, q3);
    for (int k = 0; k < scnt; k += 4) {
        float v0 = w0, v1 = w1, v2 = w2, v3 = w3;
        uint2 p0 = q0, p1 = q1, p2 = q2, p3 = q3;
        LDQ1(k + 4, w0, q0); LDQ1(k + 5, w1, q1);
        LDQ1(k + 6, w2, q2); LDQ1(k + 7, w3, q3);
        ACCUMW1(p0, v0);
        ACCUMW1(p1, v1);
        ACCUMW1(p2, v2);
        ACCUMW1(p3, v3);
    }

    // ---- slow path ----
    if (cnt > CAP1) {
        for (int k2 = CAP1; k2 < cnt; ++k2) {
            int n = srcs[beg + k2];
            float e = sv[n] + d_i;
            float wgt = __expf(fminf(fmaxf(e, NEG_SLOPE * e), 60.f));
            if (gl == 0) atomicAdd(&lden[sub], wgt);
            uint2 q2v = *(const uint2*)(hrow + (size_t)n * 64);
            ACCUMW1(q2v, wgt);
        }
    }

    // ---- final ----
    if (valid) {
        float e_self = sv[i] + d_i;
        float wself = __expf(fminf(fmaxf(e_self, NEG_SLOPE * e_self), 60.f));
        uint2 qs = *(const uint2*)&hb[(size_t)i * 64 + gl * 4];
        ACCUMW1(qs, wself);
        float rden = 1.f / (lden[sub] + wself + 1e-16f);
        const float* bb = bias + gl * 4;
        uint2 o;
        o.x = (uint)f2bf(ax[0].x * rden + bb[0]) | ((uint)f2bf(ax[0].y * rden + bb[1]) << 16);
        o.y = (uint)f2bf(ax[1].x * rden + bb[2]) | ((uint)f2bf(ax[1].y * rden + bb[3]) << 16);
        *(uint2*)&zb[(size_t)i * 64 + gl * 4] = o;
    }
}

// ---------------- BatchNorm stats: vectorized grid-stride partials ----------------

template <int F>
__launch_bounds__(256)
__global__ void bn_stats_kernel(const ushort* __restrict__ x, float* __restrict__ ps,
                                float* __restrict__ pq, int N) {
    constexpr int OCT = F / 8;
    __shared__ float lds_s[F], lds_q[F];
    int t = threadIdx.x;
    if (t < F) { lds_s[t] = 0.f; lds_q[t] = 0.f; }
    __syncthreads();

    float s[8] = {}, q[8] = {};
    int total8 = N * F / 8;
    for (int idx = blockIdx.x * 256 + t; idx < total8; idx += NB_RED * 256) {
        uint4 v = ((const uint4*)x)[idx];
        uint pr[4] = {v.x, v.y, v.z, v.w};
#pragma unroll
        for (int k = 0; k < 4; ++k) {
            float a = bf2f(pr[k] & 0xffffu);
            float b = bf2f(pr[k] >> 16);
            s[2 * k] += a;     q[2 * k] += a * a;
            s[2 * k + 1] += b; q[2 * k + 1] += b * b;
        }
    }
    int co = t % OCT;
#pragma unroll
    for (int j = 0; j < 8; ++j) {
        atomicAdd(&lds_s[co * 8 + j], s[j]);
        atomicAdd(&lds_q[co * 8 + j], q[j]);
    }
    __syncthreads();
    if (t < F) {
        ps[blockIdx.x * F + t] = lds_s[t];
        pq[blockIdx.x * F + t] = lds_q[t];
    }
}

__global__ void bn_final_kernel(const float* __restrict__ ps, const float* __restrict__ pq,
                                const float* __restrict__ g, const float* __restrict__ be,
                                float* __restrict__ scale, float* __restrict__ shift,
                                int N, int F) {
    int t = threadIdx.x;
    if (t < F) {
        float s = 0.f, q = 0.f;
        for (int b = 0; b < NB_RED; ++b) { s += ps[b * F + t]; q += pq[b * F + t]; }
        float mean = s / (float)N;
        float var = q / (float)N - mean * mean;
        float sc = g[t] * rsqrtf(var + BN_EPS);
        scale[t] = sc;
        shift[t] = be[t] - sc * mean;
    }
}

__global__ void bn_apply_kernel(uint* __restrict__ x, const float* __restrict__ scale,
                                const float* __restrict__ shift, int totalPairs, int Fmask) {
    int i = blockIdx.x * blockDim.x + threadIdx.x;
    if (i < totalPairs) {
        uint p = x[i];
        int c0 = (2 * i) & Fmask;
        float v0 = fmaxf(bf2f(p & 0xffffu) * scale[c0] + shift[c0], 0.f);
        float v1 = fmaxf(bf2f(p >> 16) * scale[c0 + 1] + shift[c0 + 1], 0.f);
        x[i] = (uint)f2bf(v0) | ((uint)f2bf(v1) << 16);
    }
}

// ---------------- pooling (BN+ReLU fused, vectorized) ----------------

__launch_bounds__(256)
__global__ void pool_kernel(const ushort* __restrict__ y, const float* __restrict__ scale,
                            const float* __restrict__ shift, float* __restrict__ psum,
                            float* __restrict__ pmax, int N) {
    constexpr int F = 64, OCT = 8;
    __shared__ float lds_s[F];
    __shared__ uint lds_m[F];
    int t = threadIdx.x;
    if (t < F) { lds_s[t] = 0.f; lds_m[t] = 0u; }
    __syncthreads();

    int co = t % OCT;
    float sc[8], sh[8];
#pragma unroll
    for (int j = 0; j < 8; ++j) { sc[j] = scale[co * 8 + j]; sh[j] = shift[co * 8 + j]; }

    float s[8] = {}, m[8] = {};
    int total8 = N * F / 8;
    for (int idx = blockIdx.x * 256 + t; idx < total8; idx += NB_RED * 256) {
        uint4 v = ((const uint4*)y)[idx];
        uint pr[4] = {v.x, v.y, v.z, v.w};
#pragma unroll
        for (int k = 0; k < 4; ++k) {
            float a = fmaxf(bf2f(pr[k] & 0xffffu) * sc[2 * k] + sh[2 * k], 0.f);
            float b = fmaxf(bf2f(pr[k] >> 16) * sc[2 * k + 1] + sh[2 * k + 1], 0.f);
            s[2 * k] += a;     m[2 * k] = fmaxf(m[2 * k], a);
            s[2 * k + 1] += b; m[2 * k + 1] = fmaxf(m[2 * k + 1], b);
        }
    }
#pragma unroll
    for (int j = 0; j < 8; ++j) {
        atomicAdd(&lds_s[co * 8 + j], s[j]);
        atomicMax(&lds_m[co * 8 + j], __float_as_uint(m[j]));
    }
    __syncthreads();
    if (t < F) {
        psum[blockIdx.x * F + t] = lds_s[t];
        pmax[blockIdx.x * F + t] = __uint_as_float(lds_m[t]);
    }
}

__global__ void classify_kernel(const float* __restrict__ psum, const float* __restrict__ pmax,
                                const float* __restrict__ Wc1, const float* __restrict__ bc1,
                                const float* __restrict__ Wc2, const float* __restrict__ bc2,
                                float* __restrict__ out, int N) {
    __shared__ float pooled[128];
    __shared__ float z[64];
    int t = threadIdx.x;   // 128 threads
    if (t < 64) {
        float s = 0.f;
        for (int b = 0; b < NB_RED; ++b) s += psum[b * 64 + t];
        pooled[t] = s / (float)N;
    } else {
        int c = t - 64;
        float m = 0.f;
        for (int b = 0; b < NB_RED; ++b) m = fmaxf(m, pmax[b * 64 + c]);
        pooled[t] = m;
    }
    __syncthreads();
    if (t < 64) {
        float a = bc1[t];
        for (int k = 0; k < 128; ++k) a += pooled[k] * Wc1[k * 64 + t];
        z[t] = a > 0.f ? a : 0.f;
    }
    __syncthreads();
    if (t < 2) {
        float a = bc2[t];
        for (int j = 0; j < 64; ++j) a += z[j] * Wc2[j * 2 + t];
        out[t] = a;
    }
}

// ---------------- driver ----------------

extern "C" void kernel_launch(void* const* d_in, const int* in_sizes, int n_in,
                              void* d_out, int out_size, void* d_ws, size_t ws_size,
                              hipStream_t stream) {
    const float* x   = (const float*)d_in[0];
    const int*   ei  = (const int*)d_in[1];
    const float* W0  = (const float*)d_in[2];  const float* b0  = (const float*)d_in[3];
    const float* as0 = (const float*)d_in[4];  const float* ad0 = (const float*)d_in[5];
    const float* g0  = (const float*)d_in[6];  const float* be0 = (const float*)d_in[7];
    const float* W1  = (const float*)d_in[8];  const float* b1  = (const float*)d_in[9];
    const float* as1 = (const float*)d_in[10]; const float* ad1 = (const float*)d_in[11];
    const float* g1  = (const float*)d_in[12]; const float* be1 = (const float*)d_in[13];
    const float* W2  = (const float*)d_in[14]; const float* b2  = (const float*)d_in[15];
    const float* as2 = (const float*)d_in[16]; const float* ad2 = (const float*)d_in[17];
    const float* g2  = (const float*)d_in[18]; const float* be2 = (const float*)d_in[19];
    const float* Wc1 = (const float*)d_in[20]; const float* bc1 = (const float*)d_in[21];
    const float* Wc2 = (const float*)d_in[22]; const float* bc2 = (const float*)d_in[23];
    float* out = (float*)d_out;

    const int N = in_sizes[0] / 128;            // 50000
    const int E = in_sizes[1] / 2;              // 800000
    const int Mpad = ((N + 127) / 128) * 128;   // 50048
    const int NB_SCAN = (N + 1023) / 1024;      // 49
    const int NBROW = Mpad / 128;               // 391
    const int NB_AGG = (N + 3) / 4;             // 12500

    char* ws = (char*)d_ws;
    size_t o = 0;
    auto alloc = [&](size_t bytes) -> void* {
        void* p = ws + o;
        o = (o + bytes + 255) & ~(size_t)255;
        return p;
    };
    int*    deg     = (int*)alloc((size_t)N * 4);
    int*    offsets = (int*)alloc((size_t)(N + 1) * 4);
    int*    cursor  = (int*)alloc((size_t)N * 4);
    int*    srcs    = (int*)alloc((size_t)E * 4);
    int*    bsum    = (int*)alloc((size_t)NB_SCAN * 4);
    int*    bexcl   = (int*)alloc((size_t)NB_SCAN * 4);
    ushort* xb      = (ushort*)alloc((size_t)Mpad * 128 * 2);
    ushort* w0t     = (ushort*)alloc((size_t)256 * 128 * 2);
    ushort* w1t     = (ushort*)alloc((size_t)256 * 256 * 2);
    ushort* w2t     = (ushort*)alloc((size_t)64 * 256 * 2);
    ushort* hb      = (ushort*)alloc((size_t)Mpad * 256 * 2);
    ushort* zb      = (ushort*)alloc((size_t)Mpad * 256 * 2);
    float*  sv      = (float*)alloc((size_t)Mpad * 4 * 4);
    float*  dv      = (float*)alloc((size_t)Mpad * 4 * 4);
    float*  ps      = (float*)alloc((size_t)NB_RED * 256 * 4);
    float*  pq      = (float*)alloc((size_t)NB_RED * 256 * 4);
    float*  scale   = (float*)alloc(256 * 4);
    float*  shift   = (float*)alloc(256 * 4);
    float*  psum    = (float*)alloc((size_t)NB_RED * 64 * 4);
    float*  pmax    = (float*)alloc((size_t)NB_RED * 64 * 4);

    // ---- prep (cvt + transpose + histogram) ----
    (void)hipMemsetAsync(deg, 0, (size_t)N * 4, stream);
    int prep_total = Mpad * 128 + 32768 + 65536 + 16384 + E;
    prep_kernel<<<(prep_total + 255) / 256, 256, 0, stream>>>(
        x, xb, N * 128, Mpad * 128, W0, w0t, W1, w1t, W2, w2t, ei, deg, E);

    // ---- CSR scan + scatter ----
    scan_part<<<NB_SCAN, 256, 0, stream>>>(deg, offsets, bsum, N);
    scan_top<<<1, 64, 0, stream>>>(bsum, bexcl, NB_SCAN, offsets, N);
    scan_add<<<NB_SCAN, 256, 0, stream>>>(offsets, cursor, bexcl, N);
    scatter_kernel<<<(E + 255) / 256, 256, 0, stream>>>(ei, cursor, srcs, E);

    // ---- layer 0 ----
    {
        mfma_gemm_bt<128, 4><<<NBROW * 2, 256, 0, stream>>>(xb, w0t, hb, as0, ad0, sv, dv, 128, 256);
        agg4_kernel<<<NB_AGG, 128, 0, stream>>>(hb, sv, dv, offsets, srcs, b0, zb, N);
        bn_stats_kernel<256><<<NB_RED, 256, 0, stream>>>(zb, ps, pq, N);
        bn_final_kernel<<<1, 256, 0, stream>>>(ps, pq, g0, be0, scale, shift, N, 256);
        bn_apply_kernel<<<(N * 128 + 255) / 256, 256, 0, stream>>>((uint*)zb, scale, shift,
                                                                   N * 128, 255);
    }
    // ---- layer 1 ----
    {
        mfma_gemm_bt<128, 4><<<NBROW * 2, 256, 0, stream>>>(zb, w1t, hb, as1, ad1, sv, dv, 256, 256);
        agg4_kernel<<<NB_AGG, 128, 0, stream>>>(hb, sv, dv, offsets, srcs, b1, zb, N);
        bn_stats_kernel<256><<<NB_RED, 256, 0, stream>>>(zb, ps, pq, N);
        bn_final_kernel<<<1, 256, 0, stream>>>(ps, pq, g1, be1, scale, shift, N, 256);
        bn_apply_kernel<<<(N * 128 + 255) / 256, 256, 0, stream>>>((uint*)zb, scale, shift,
                                                                   N * 128, 255);
    }
    // ---- layer 2 (1 head, F=64); BN-apply fused into pool ----
    {
        mfma_gemm_bt<64, 1><<<NBROW, 256, 0, stream>>>(zb, w2t, hb, as2, ad2, sv, dv, 256, 64);
        agg1_kernel<<<NB_AGG, 64, 0, stream>>>(hb, sv, dv, offsets, srcs, b2, zb, N);
        bn_stats_kernel<64><<<NB_RED, 256, 0, stream>>>(zb, ps, pq, N);
        bn_final_kernel<<<1, 64, 0, stream>>>(ps, pq, g2, be2, scale, shift, N, 64);
    }

    // ---- pooling (BN+ReLU fused) + classifier ----
    pool_kernel<<<NB_RED, 256, 0, stream>>>(zb, scale, shift, psum, pmax, N);
    classify_kernel<<<1, 128, 0, stream>>>(psum, pmax, Wc1, bc1, Wc2, bc2, out, N);
}